// Round 1
// baseline (631.789 us; speedup 1.0000x reference)
//
#include <hip/hip_runtime.h>
#include <math.h>

#define BB 8
#define CC 128
#define NN 65536
#define LL 64

// ---------------- kernel 1: streaming accumulation ----------------
// grid = BB * (NN/1024) = 512 blocks, 256 threads
#define CHUNK 64
#define NCHUNKS 16
#define PTS_PER_BLOCK (CHUNK * NCHUNKS)   // 1024
#define K1_BLOCKS (BB * (NN / PTS_PER_BLOCK))
#define ACC_STRIDE 129                    // pad: bank = (l + c) % 32

__global__ __launch_bounds__(256, 2)
void k1_accumulate(const float* __restrict__ pred, const int* __restrict__ label,
                   float* __restrict__ gsum, float* __restrict__ gcnt,
                   float* __restrict__ gv)
{
    __shared__ float acc[LL * ACC_STRIDE];   // 33 KB  per-label per-channel sums
    __shared__ float part[16 * CHUNK * 2];   // 8 KB   S1/S2 partials: part[cl][p][2]
    __shared__ float vacc[LL];
    __shared__ float cacc[LL];

    const int tid = threadIdx.x;
    const int pg  = tid & 15;    // point-group: covers points 4*pg .. 4*pg+3
    const int cl  = tid >> 4;    // channel class: c = cl + 16*k

    for (int i = tid; i < LL * ACC_STRIDE; i += 256) acc[i] = 0.f;
    if (tid < LL) { vacc[tid] = 0.f; cacc[tid] = 0.f; }
    __syncthreads();

    const int blocks_per_b = NN / PTS_PER_BLOCK;   // 64
    const int b     = blockIdx.x / blocks_per_b;
    const int nbase = (blockIdx.x % blocks_per_b) * PTS_PER_BLOCK;

    const float* __restrict__ predb = pred + (size_t)b * CC * NN;
    const int*   __restrict__ labb  = label + (size_t)b * NN;

    for (int ch = 0; ch < NCHUNKS; ++ch) {
        const int n0 = nbase + ch * CHUNK;

        const int4 lab = *(const int4*)(labb + n0 + 4 * pg);
        const int l0 = lab.x * ACC_STRIDE, l1 = lab.y * ACC_STRIDE;
        const int l2 = lab.z * ACC_STRIDE, l3 = lab.w * ACC_STRIDE;

        // 8 independent float4 loads: 4 points x 8 channels each
        float4 xv[8];
        #pragma unroll
        for (int k = 0; k < 8; ++k) {
            const int c = cl + 16 * k;
            xv[k] = *(const float4*)(predb + (size_t)c * NN + n0 + 4 * pg);
        }

        float s10 = 0.f, s20 = 0.f, s11 = 0.f, s21 = 0.f;
        float s12 = 0.f, s22 = 0.f, s13 = 0.f, s23 = 0.f;
        #pragma unroll
        for (int k = 0; k < 8; ++k) {
            const int c = cl + 16 * k;
            const float4 x = xv[k];
            atomicAdd(&acc[l0 + c], x.x);
            atomicAdd(&acc[l1 + c], x.y);
            atomicAdd(&acc[l2 + c], x.z);
            atomicAdd(&acc[l3 + c], x.w);
            s10 += x.x; s20 += x.x * x.x;
            s11 += x.y; s21 += x.y * x.y;
            s12 += x.z; s22 += x.z * x.z;
            s13 += x.w; s23 += x.w * x.w;
        }

        // stash S1/S2 partials (8 consecutive floats -> 2x float4, 32B aligned)
        float4* pp = (float4*)&part[cl * CHUNK * 2 + 8 * pg];
        pp[0] = make_float4(s10, s20, s11, s21);
        pp[1] = make_float4(s12, s22, s13, s23);
        __syncthreads();

        if (tid < CHUNK) {
            float s1 = 0.f, s2 = 0.f;
            #pragma unroll
            for (int q = 0; q < 16; ++q) {
                const float2 t = *(const float2*)&part[q * CHUNK * 2 + 2 * tid];
                s1 += t.x; s2 += t.y;
            }
            float sq = s2 - s1 * s1 * (1.0f / CC);
            sq = sq > 0.f ? sq : 0.f;
            const float d = sqrtf(sq) - 0.5f;      // D_VAR
            const float v = d > 0.f ? d * d : 0.f;
            const int l = labb[n0 + tid];
            atomicAdd(&vacc[l], v);
            atomicAdd(&cacc[l], 1.0f);
        }
        __syncthreads();
    }

    // flush block accumulators to global
    float* __restrict__ gs = gsum + (size_t)b * LL * CC;
    for (int i = tid; i < LL * CC; i += 256) {
        atomicAdd(&gs[i], acc[(i >> 7) * ACC_STRIDE + (i & 127)]);
    }
    if (tid < LL) {
        atomicAdd(&gcnt[b * LL + tid], cacc[tid]);
        atomicAdd(&gv[b * LL + tid], vacc[tid]);
    }
}

// ---------------- kernel 2: finalize (tiny) ----------------
// grid = BB*8 = 64 blocks; block (b, strip) computes hinge for c in [16*strip,16*strip+16) x all d
#define CEN_STRIDE 132   // multiple of 4 -> 16B-aligned float4 rows

__global__ __launch_bounds__(256)
void k2_finalize(const float* __restrict__ gsum, const float* __restrict__ gcnt,
                 const float* __restrict__ gv, float* __restrict__ out)
{
    __shared__ float cen[LL * CEN_STRIDE];
    __shared__ float invc[LL];
    __shared__ float red[256];

    const int tid   = threadIdx.x;
    const int b     = blockIdx.x >> 3;
    const int strip = blockIdx.x & 7;

    if (tid < LL) invc[tid] = 1.0f / gcnt[b * LL + tid];
    __syncthreads();

    const float* __restrict__ gs = gsum + (size_t)b * LL * CC;
    for (int i = tid; i < LL * CC; i += 256) {
        const int l = i >> 7, c = i & 127;
        cen[l * CEN_STRIDE + c] = gs[i] * invc[l];
    }
    __syncthreads();

    const int c  = strip * 16 + (tid >> 4);
    const int d0 = (tid & 15) * 8;

    float areg[LL];
    #pragma unroll
    for (int l = 0; l < LL; ++l) areg[l] = cen[l * CEN_STRIDE + c];

    float sqd[8] = {0.f, 0.f, 0.f, 0.f, 0.f, 0.f, 0.f, 0.f};
    #pragma unroll
    for (int l = 0; l < LL; ++l) {
        const float4 b0 = *(const float4*)&cen[l * CEN_STRIDE + d0];
        const float4 b1 = *(const float4*)&cen[l * CEN_STRIDE + d0 + 4];
        const float a = areg[l];
        float t;
        t = a - b0.x; sqd[0] += t * t;
        t = a - b0.y; sqd[1] += t * t;
        t = a - b0.z; sqd[2] += t * t;
        t = a - b0.w; sqd[3] += t * t;
        t = a - b1.x; sqd[4] += t * t;
        t = a - b1.y; sqd[5] += t * t;
        t = a - b1.z; sqd[6] += t * t;
        t = a - b1.w; sqd[7] += t * t;
    }

    float hsum = 0.f;
    #pragma unroll
    for (int j = 0; j < 8; ++j) {
        const float dist = sqd[j] > 0.f ? sqrtf(sqd[j]) : 0.f;
        float h = 3.0f - dist;                 // 2*D_DIST
        h = h > 0.f ? h : 0.f;
        hsum += h * h;
    }
    // denom = 2*L*(L-1+1e-16) = 8064
    float my = hsum * (1.0f / 8064.0f);

    if (strip == 0) {
        if (tid < CC) {   // l_reg: 0.001 * sum_c sqrt(sum_l cen^2) / L
            float s = 0.f;
            #pragma unroll
            for (int l = 0; l < LL; ++l) {
                const float v = cen[l * CEN_STRIDE + tid];
                s += v * v;
            }
            my += 0.001f * sqrtf(s) * (1.0f / LL);
        }
        if (tid < LL) {   // var: sum_l (v_sum/cnt) / L
            my += gv[b * LL + tid] * invc[tid] * (1.0f / LL);
        }
    }

    red[tid] = my;
    __syncthreads();
    for (int s = 128; s > 0; s >>= 1) {
        if (tid < s) red[tid] += red[tid + s];
        __syncthreads();
    }
    if (tid == 0) atomicAdd(out, red[0]);
}

extern "C" void kernel_launch(void* const* d_in, const int* in_sizes, int n_in,
                              void* d_out, int out_size, void* d_ws, size_t ws_size,
                              hipStream_t stream) {
    (void)in_sizes; (void)n_in; (void)out_size; (void)ws_size;
    const float* pred  = (const float*)d_in[0];
    const int*   label = (const int*)d_in[1];
    float* out  = (float*)d_out;
    float* gsum = (float*)d_ws;                 // [B][L][C] = 65536 floats
    float* gcnt = gsum + BB * LL * CC;          // [B][L]    = 512
    float* gv   = gcnt + BB * LL;               // [B][L]    = 512

    hipMemsetAsync(d_ws, 0, (size_t)(BB * LL * CC + 2 * BB * LL) * sizeof(float), stream);
    hipMemsetAsync(d_out, 0, sizeof(float), stream);

    k1_accumulate<<<K1_BLOCKS, 256, 0, stream>>>(pred, label, gsum, gcnt, gv);
    k2_finalize<<<BB * 8, 256, 0, stream>>>(gsum, gcnt, gv, out);
}

// Round 2
// 623.572 us; speedup vs baseline: 1.0132x; 1.0132x over previous
//
#include <hip/hip_runtime.h>
#include <math.h>

#define BB 8
#define CC 128
#define NN 65536
#define LL 64

// ---------------- kernel 1: streaming accumulation ----------------
#define CHUNK 64
#define NCHUNKS 8
#define PTS_PER_BLOCK (CHUNK * NCHUNKS)   // 512
#define K1_BLOCKS (BB * (NN / PTS_PER_BLOCK))  // 1024
#define ACC_STRIDE 129                    // pad: bank = (l + c) % 32

__device__ __forceinline__ void atomAddF(float* p, float v) {
    unsafeAtomicAdd(p, v);   // native ds_add_f32 / global_atomic_add_f32
}

__global__ __launch_bounds__(256, 3)
void k1_accumulate(const float* __restrict__ pred, const int* __restrict__ label,
                   float* __restrict__ gsum, float* __restrict__ gcnt,
                   float* __restrict__ gv)
{
    __shared__ float acc[LL * ACC_STRIDE];   // 33 KB  per-label per-channel sums
    __shared__ float part[16 * CHUNK * 2];   // 8 KB   S1/S2 partials: part[cl][p][2]
    __shared__ float vacc[LL];
    __shared__ float cacc[LL];

    const int tid = threadIdx.x;
    const int pg  = tid & 15;    // point-group: covers points 4*pg .. 4*pg+3
    const int cl  = tid >> 4;    // channel class: c = cl + 16*k

    for (int i = tid; i < LL * ACC_STRIDE; i += 256) acc[i] = 0.f;
    if (tid < LL) { vacc[tid] = 0.f; cacc[tid] = 0.f; }
    __syncthreads();

    const int blocks_per_b = NN / PTS_PER_BLOCK;   // 128
    const int b     = blockIdx.x / blocks_per_b;
    const int nbase = (blockIdx.x % blocks_per_b) * PTS_PER_BLOCK;

    const float* __restrict__ predb = pred + (size_t)b * CC * NN;
    const int*   __restrict__ labb  = label + (size_t)b * NN;

    for (int ch = 0; ch < NCHUNKS; ++ch) {
        const int n0 = nbase + ch * CHUNK;

        const int4 lab = *(const int4*)(labb + n0 + 4 * pg);
        const int l0 = lab.x * ACC_STRIDE, l1 = lab.y * ACC_STRIDE;
        const int l2 = lab.z * ACC_STRIDE, l3 = lab.w * ACC_STRIDE;

        // 8 independent float4 loads: 4 points x 8 channels each
        float4 xv[8];
        #pragma unroll
        for (int k = 0; k < 8; ++k) {
            const int c = cl + 16 * k;
            xv[k] = *(const float4*)(predb + (size_t)c * NN + n0 + 4 * pg);
        }

        float s10 = 0.f, s20 = 0.f, s11 = 0.f, s21 = 0.f;
        float s12 = 0.f, s22 = 0.f, s13 = 0.f, s23 = 0.f;
        #pragma unroll
        for (int k = 0; k < 8; ++k) {
            const int c = cl + 16 * k;
            const float4 x = xv[k];
            atomAddF(&acc[l0 + c], x.x);
            atomAddF(&acc[l1 + c], x.y);
            atomAddF(&acc[l2 + c], x.z);
            atomAddF(&acc[l3 + c], x.w);
            s10 += x.x; s20 += x.x * x.x;
            s11 += x.y; s21 += x.y * x.y;
            s12 += x.z; s22 += x.z * x.z;
            s13 += x.w; s23 += x.w * x.w;
        }

        // stash S1/S2 partials (8 consecutive floats -> 2x float4, 32B aligned)
        float4* pp = (float4*)&part[cl * CHUNK * 2 + 8 * pg];
        pp[0] = make_float4(s10, s20, s11, s21);
        pp[1] = make_float4(s12, s22, s13, s23);
        __syncthreads();

        if (tid < CHUNK) {
            float s1 = 0.f, s2 = 0.f;
            #pragma unroll
            for (int q = 0; q < 16; ++q) {
                const float2 t = *(const float2*)&part[q * CHUNK * 2 + 2 * tid];
                s1 += t.x; s2 += t.y;
            }
            float sq = s2 - s1 * s1 * (1.0f / CC);
            sq = sq > 0.f ? sq : 0.f;
            const float d = sqrtf(sq) - 0.5f;      // D_VAR
            const float v = d > 0.f ? d * d : 0.f;
            const int l = labb[n0 + tid];
            atomAddF(&vacc[l], v);
            atomAddF(&cacc[l], 1.0f);
        }
        __syncthreads();
    }

    // flush block accumulators to global
    float* __restrict__ gs = gsum + (size_t)b * LL * CC;
    for (int i = tid; i < LL * CC; i += 256) {
        atomAddF(&gs[i], acc[(i >> 7) * ACC_STRIDE + (i & 127)]);
    }
    if (tid < LL) {
        atomAddF(&gcnt[b * LL + tid], cacc[tid]);
        atomAddF(&gv[b * LL + tid], vacc[tid]);
    }
}

// ---------------- kernel 2: finalize (tiny) ----------------
#define CEN_STRIDE 132   // multiple of 4 -> 16B-aligned float4 rows

__global__ __launch_bounds__(256)
void k2_finalize(const float* __restrict__ gsum, const float* __restrict__ gcnt,
                 const float* __restrict__ gv, float* __restrict__ out)
{
    __shared__ float cen[LL * CEN_STRIDE];
    __shared__ float invc[LL];
    __shared__ float red[256];

    const int tid   = threadIdx.x;
    const int b     = blockIdx.x >> 3;
    const int strip = blockIdx.x & 7;

    if (tid < LL) invc[tid] = 1.0f / gcnt[b * LL + tid];
    __syncthreads();

    const float* __restrict__ gs = gsum + (size_t)b * LL * CC;
    for (int i = tid; i < LL * CC; i += 256) {
        const int l = i >> 7, c = i & 127;
        cen[l * CEN_STRIDE + c] = gs[i] * invc[l];
    }
    __syncthreads();

    const int c  = strip * 16 + (tid >> 4);
    const int d0 = (tid & 15) * 8;

    float areg[LL];
    #pragma unroll
    for (int l = 0; l < LL; ++l) areg[l] = cen[l * CEN_STRIDE + c];

    float sqd[8] = {0.f, 0.f, 0.f, 0.f, 0.f, 0.f, 0.f, 0.f};
    #pragma unroll
    for (int l = 0; l < LL; ++l) {
        const float4 b0 = *(const float4*)&cen[l * CEN_STRIDE + d0];
        const float4 b1 = *(const float4*)&cen[l * CEN_STRIDE + d0 + 4];
        const float a = areg[l];
        float t;
        t = a - b0.x; sqd[0] += t * t;
        t = a - b0.y; sqd[1] += t * t;
        t = a - b0.z; sqd[2] += t * t;
        t = a - b0.w; sqd[3] += t * t;
        t = a - b1.x; sqd[4] += t * t;
        t = a - b1.y; sqd[5] += t * t;
        t = a - b1.z; sqd[6] += t * t;
        t = a - b1.w; sqd[7] += t * t;
    }

    float hsum = 0.f;
    #pragma unroll
    for (int j = 0; j < 8; ++j) {
        const float dist = sqd[j] > 0.f ? sqrtf(sqd[j]) : 0.f;
        float h = 3.0f - dist;                 // 2*D_DIST
        h = h > 0.f ? h : 0.f;
        hsum += h * h;
    }
    // denom = 2*L*(L-1+1e-16) = 8064
    float my = hsum * (1.0f / 8064.0f);

    if (strip == 0) {
        if (tid < CC) {   // l_reg: 0.001 * sum_c sqrt(sum_l cen^2) / L
            float s = 0.f;
            #pragma unroll
            for (int l = 0; l < LL; ++l) {
                const float v = cen[l * CEN_STRIDE + tid];
                s += v * v;
            }
            my += 0.001f * sqrtf(s) * (1.0f / LL);
        }
        if (tid < LL) {   // var: sum_l (v_sum/cnt) / L
            my += gv[b * LL + tid] * invc[tid] * (1.0f / LL);
        }
    }

    red[tid] = my;
    __syncthreads();
    for (int s = 128; s > 0; s >>= 1) {
        if (tid < s) red[tid] += red[tid + s];
        __syncthreads();
    }
    if (tid == 0) unsafeAtomicAdd(out, red[0]);
}

extern "C" void kernel_launch(void* const* d_in, const int* in_sizes, int n_in,
                              void* d_out, int out_size, void* d_ws, size_t ws_size,
                              hipStream_t stream) {
    (void)in_sizes; (void)n_in; (void)out_size; (void)ws_size;
    const float* pred  = (const float*)d_in[0];
    const int*   label = (const int*)d_in[1];
    float* out  = (float*)d_out;
    float* gsum = (float*)d_ws;                 // [B][L][C] = 65536 floats
    float* gcnt = gsum + BB * LL * CC;          // [B][L]    = 512
    float* gv   = gcnt + BB * LL;               // [B][L]    = 512

    hipMemsetAsync(d_ws, 0, (size_t)(BB * LL * CC + 2 * BB * LL) * sizeof(float), stream);
    hipMemsetAsync(d_out, 0, sizeof(float), stream);

    k1_accumulate<<<K1_BLOCKS, 256, 0, stream>>>(pred, label, gsum, gcnt, gv);
    k2_finalize<<<BB * 8, 256, 0, stream>>>(gsum, gcnt, gv, out);
}

// Round 3
// 536.582 us; speedup vs baseline: 1.1774x; 1.1621x over previous
//
#include <hip/hip_runtime.h>
#include <math.h>

#define BB 8
#define CC 128
#define NN 65536
#define LL 64

#define PTS 512
#define CHK 128
#define NCHK (PTS/CHK)                 // 4
#define BLOCKS_PER_B (NN/PTS)          // 128
#define K1_BLOCKS (BB*BLOCKS_PER_B)    // 1024

typedef __attribute__((ext_vector_type(16))) float f32x16;
typedef __attribute__((ext_vector_type(8)))  short s16x8;

union V16 { int4 i; uint4 u; s16x8 s; };

__device__ __forceinline__ void atomAddF(float* p, float v) { unsafeAtomicAdd(p, v); }

__device__ __forceinline__ unsigned bf16rne(float f) {
    unsigned u = __builtin_bit_cast(unsigned, f);
    return (u + 0x7fffu + ((u >> 16) & 1u)) >> 16;
}
__device__ __forceinline__ unsigned packbf(float lo, float hi) {
    return bf16rne(lo) | (bf16rne(hi) << 16);
}
__device__ __forceinline__ unsigned oh2(int a, int b, int t) {
    return (a == t ? 0x3F80u : 0u) | (b == t ? 0x3F800000u : 0u);
}

// one block: 512 points of one batch; centers via MFMA (pred x onehot), var via
// swizzled-LDS transposed read. No scattered per-element LDS atomics anywhere.
__global__ __launch_bounds__(256, 3)
void k1_mfma(const float* __restrict__ pred, const int* __restrict__ label,
             float* __restrict__ gsum, float* __restrict__ gcnt, float* __restrict__ gv)
{
    // bf16 chunk [c=128][n=128], row stride 64 uints (128 bf16), 16B-quad swizzle q^=c&15
    __shared__ __align__(16) unsigned pred_lds[CC * 64];   // 32 KB
    __shared__ __align__(16) int lab_s[PTS];               // 2 KB
    __shared__ __align__(16) float4 pr[256];               // 4 KB  S1/S2 partials
    __shared__ float vacc[LL];
    __shared__ unsigned cnt[LL];

    const int tid  = threadIdx.x;
    const int wv   = tid >> 6;      // wave = channel tile (32 ch)
    const int lane = tid & 63;

    const int b   = blockIdx.x / BLOCKS_PER_B;
    const int n0b = (blockIdx.x % BLOCKS_PER_B) * PTS;

    const float* __restrict__ predb = pred + (size_t)b * CC * NN;
    const int*   __restrict__ labb  = label + (size_t)b * NN + n0b;

    if (tid < LL) { vacc[tid] = 0.f; cnt[tid] = 0u; }
    if (tid < PTS/4) *(int4*)&lab_s[4*tid] = *(const int4*)(labb + 4*tid);
    __syncthreads();

    { const int l0 = lab_s[2*tid], l1 = lab_s[2*tid+1];
      atomicAdd(&cnt[l0], 1u); atomicAdd(&cnt[l1], 1u); }

    f32x16 acc0, acc1;
    #pragma unroll
    for (int i = 0; i < 16; ++i) { acc0[i] = 0.f; acc1[i] = 0.f; }

    const int src_c = tid & 127;    // staging row (channel)
    const int src_h = tid >> 7;     // staging half (64 pts)
    const int t0lab = lane & 31;
    const int khalf = lane >> 5;
    const int arow  = (wv << 5) + (lane & 31);

    for (int ch = 0; ch < NCHK; ++ch) {
        const int n0 = n0b + ch * CHK;

        // ---- stage: 128x128 f32 -> bf16 LDS (coalesced 4-line/thread reads) ----
        const float* gp = predb + (size_t)src_c * NN + n0 + src_h * 64;
        float4 r[16];
        #pragma unroll
        for (int j = 0; j < 16; ++j) r[j] = *(const float4*)(gp + 4*j);
        #pragma unroll
        for (int i = 0; i < 8; ++i) {
            uint4 w;
            w.x = packbf(r[2*i].x,   r[2*i].y);
            w.y = packbf(r[2*i].z,   r[2*i].w);
            w.z = packbf(r[2*i+1].x, r[2*i+1].y);
            w.w = packbf(r[2*i+1].z, r[2*i+1].w);
            const int q  = 8*src_h + i;
            const int qs = q ^ (src_c & 15);
            *(uint4*)&pred_lds[src_c*64 + qs*4] = w;
        }
        __syncthreads();   // b1

        // ---- MFMA: A = pred[32ch x 16pts], B = onehot built from compares ----
        #pragma unroll
        for (int ks = 0; ks < 8; ++ks) {
            const int k0 = ks * 16;
            const int q  = (k0 >> 3) + khalf;
            const int qs = q ^ (arow & 15);
            V16 a; a.i = *(const int4*)&pred_lds[arow*64 + qs*4];
            const int lbase = ch*CHK + k0 + (khalf << 3);
            const int4 la = *(const int4*)&lab_s[lbase];
            const int4 lb = *(const int4*)&lab_s[lbase + 4];
            V16 b0, b1;
            b0.u = make_uint4(oh2(la.x,la.y,t0lab), oh2(la.z,la.w,t0lab),
                              oh2(lb.x,lb.y,t0lab), oh2(lb.z,lb.w,t0lab));
            const int t1lab = t0lab + 32;
            b1.u = make_uint4(oh2(la.x,la.y,t1lab), oh2(la.z,la.w,t1lab),
                              oh2(lb.x,lb.y,t1lab), oh2(lb.z,lb.w,t1lab));
            acc0 = __builtin_amdgcn_mfma_f32_32x32x16_bf16(a.s, b0.s, acc0, 0, 0, 0);
            acc1 = __builtin_amdgcn_mfma_f32_32x32x16_bf16(a.s, b1.s, acc1, 0, 0, 0);
        }

        // ---- S1/S2: transposed read, lane = point-pair, wave = 32-channel slice ----
        {
            const int p2 = tid & 63;
            float s1a=0.f, s2a=0.f, s1b=0.f, s2b=0.f;
            #pragma unroll
            for (int i2 = 0; i2 < 32; ++i2) {
                const int c  = (wv << 5) + i2;
                const int qs = (p2 >> 2) ^ (c & 15);
                const unsigned u = pred_lds[c*64 + qs*4 + (p2 & 3)];
                const float fa = __builtin_bit_cast(float, u << 16);
                const float fb = __builtin_bit_cast(float, u & 0xffff0000u);
                s1a += fa; s2a = fmaf(fa, fa, s2a);
                s1b += fb; s2b = fmaf(fb, fb, s2b);
            }
            pr[(p2 << 2) | wv] = make_float4(s1a, s2a, s1b, s2b);
        }
        __syncthreads();   // b2

        if (tid < 64) {
            const float4 t0 = pr[4*tid], t1 = pr[4*tid+1], t2 = pr[4*tid+2], t3 = pr[4*tid+3];
            const float s1 = t0.x+t1.x+t2.x+t3.x, s2 = t0.y+t1.y+t2.y+t3.y;
            const float u1 = t0.z+t1.z+t2.z+t3.z, u2 = t0.w+t1.w+t2.w+t3.w;
            float sqa = s2 - s1*s1*(1.0f/CC); sqa = sqa > 0.f ? sqa : 0.f;
            float sqb = u2 - u1*u1*(1.0f/CC); sqb = sqb > 0.f ? sqb : 0.f;
            const float da = sqrtf(sqa) - 0.5f, db = sqrtf(sqb) - 0.5f;
            const float va = da > 0.f ? da*da : 0.f, vb = db > 0.f ? db*db : 0.f;
            const int la0 = lab_s[ch*CHK + 2*tid], la1 = lab_s[ch*CHK + 2*tid + 1];
            atomAddF(&vacc[la0], va);
            atomAddF(&vacc[la1], vb);
        }
        // next-iter staging writes pred_lds only; combine touches pr/lab_s — no race
    }
    __syncthreads();

    // ---- flush: C/D layout col=lane&31 (label), row=(r&3)+8*(r>>2)+4*(lane>>5) (channel) ----
    float* __restrict__ gs = gsum + (size_t)b * LL * CC;
    const int col = lane & 31, rh = lane >> 5;
    #pragma unroll
    for (int r2 = 0; r2 < 16; ++r2) {
        const int chn = (wv << 5) + (r2 & 3) + ((r2 >> 2) << 3) + (rh << 2);
        atomAddF(&gs[col*CC + chn], acc0[r2]);
        atomAddF(&gs[(col+32)*CC + chn], acc1[r2]);
    }
    if (tid < LL) {
        atomAddF(&gcnt[b*LL + tid], (float)cnt[tid]);
        atomAddF(&gv[b*LL + tid], vacc[tid]);
    }
}

// ---------------- kernel 2: finalize (tiny, unchanged) ----------------
#define CEN_STRIDE 132

__global__ __launch_bounds__(256)
void k2_finalize(const float* __restrict__ gsum, const float* __restrict__ gcnt,
                 const float* __restrict__ gv, float* __restrict__ out)
{
    __shared__ float cen[LL * CEN_STRIDE];
    __shared__ float invc[LL];
    __shared__ float red[256];

    const int tid   = threadIdx.x;
    const int b     = blockIdx.x >> 3;
    const int strip = blockIdx.x & 7;

    if (tid < LL) invc[tid] = 1.0f / gcnt[b * LL + tid];
    __syncthreads();

    const float* __restrict__ gs = gsum + (size_t)b * LL * CC;
    for (int i = tid; i < LL * CC; i += 256) {
        const int l = i >> 7, c = i & 127;
        cen[l * CEN_STRIDE + c] = gs[i] * invc[l];
    }
    __syncthreads();

    const int c  = strip * 16 + (tid >> 4);
    const int d0 = (tid & 15) * 8;

    float areg[LL];
    #pragma unroll
    for (int l = 0; l < LL; ++l) areg[l] = cen[l * CEN_STRIDE + c];

    float sqd[8] = {0.f, 0.f, 0.f, 0.f, 0.f, 0.f, 0.f, 0.f};
    #pragma unroll
    for (int l = 0; l < LL; ++l) {
        const float4 b0 = *(const float4*)&cen[l * CEN_STRIDE + d0];
        const float4 b1 = *(const float4*)&cen[l * CEN_STRIDE + d0 + 4];
        const float a = areg[l];
        float t;
        t = a - b0.x; sqd[0] += t * t;
        t = a - b0.y; sqd[1] += t * t;
        t = a - b0.z; sqd[2] += t * t;
        t = a - b0.w; sqd[3] += t * t;
        t = a - b1.x; sqd[4] += t * t;
        t = a - b1.y; sqd[5] += t * t;
        t = a - b1.z; sqd[6] += t * t;
        t = a - b1.w; sqd[7] += t * t;
    }

    float hsum = 0.f;
    #pragma unroll
    for (int j = 0; j < 8; ++j) {
        const float dist = sqd[j] > 0.f ? sqrtf(sqd[j]) : 0.f;
        float h = 3.0f - dist;
        h = h > 0.f ? h : 0.f;
        hsum += h * h;
    }
    float my = hsum * (1.0f / 8064.0f);

    if (strip == 0) {
        if (tid < CC) {
            float s = 0.f;
            #pragma unroll
            for (int l = 0; l < LL; ++l) {
                const float v = cen[l * CEN_STRIDE + tid];
                s += v * v;
            }
            my += 0.001f * sqrtf(s) * (1.0f / LL);
        }
        if (tid < LL) {
            my += gv[b * LL + tid] * invc[tid] * (1.0f / LL);
        }
    }

    red[tid] = my;
    __syncthreads();
    for (int s = 128; s > 0; s >>= 1) {
        if (tid < s) red[tid] += red[tid + s];
        __syncthreads();
    }
    if (tid == 0) unsafeAtomicAdd(out, red[0]);
}

extern "C" void kernel_launch(void* const* d_in, const int* in_sizes, int n_in,
                              void* d_out, int out_size, void* d_ws, size_t ws_size,
                              hipStream_t stream) {
    (void)in_sizes; (void)n_in; (void)out_size; (void)ws_size;
    const float* pred  = (const float*)d_in[0];
    const int*   label = (const int*)d_in[1];
    float* out  = (float*)d_out;
    float* gsum = (float*)d_ws;                 // [B][L][C]
    float* gcnt = gsum + BB * LL * CC;          // [B][L]
    float* gv   = gcnt + BB * LL;               // [B][L]

    hipMemsetAsync(d_ws, 0, (size_t)(BB * LL * CC + 2 * BB * LL) * sizeof(float), stream);
    hipMemsetAsync(d_out, 0, sizeof(float), stream);

    k1_mfma<<<K1_BLOCKS, 256, 0, stream>>>(pred, label, gsum, gcnt, gv);
    k2_finalize<<<BB * 8, 256, 0, stream>>>(gsum, gcnt, gv, out);
}

// Round 4
// 420.999 us; speedup vs baseline: 1.5007x; 1.2745x over previous
//
#include <hip/hip_runtime.h>
#include <math.h>

#define BB 8
#define CC 128
#define NN 65536
#define LL 64
#define CHK 128

typedef __attribute__((ext_vector_type(16))) float f32x16;
typedef __attribute__((ext_vector_type(8)))  short s16x8;

union V16 { int4 i; uint4 u; s16x8 s; };

__device__ __forceinline__ unsigned bf16rne(float f) {
    unsigned u = __builtin_bit_cast(unsigned, f);
    return (u + 0x7fffu + ((u >> 16) & 1u)) >> 16;
}
__device__ __forceinline__ unsigned packbf(float lo, float hi) {
    return bf16rne(lo) | (bf16rne(hi) << 16);
}
__device__ __forceinline__ unsigned oh2(int a, int b, int t) {
    return (a == t ? 0x3F80u : 0u) | (b == t ? 0x3F800000u : 0u);
}

// one block: (nchk*128) points of one batch; centers via MFMA (pred x onehot).
// NO global atomics: per-block partials written coalesced in fragment order.
__global__ __launch_bounds__(256, 3)
void k1_mfma(const float* __restrict__ pred, const int* __restrict__ label,
             float* __restrict__ gpart, float* __restrict__ gcp, float* __restrict__ gvp,
             int blk_per_b, int nchk)
{
    __shared__ __align__(16) unsigned pred_lds[CC * 64];   // 32 KB bf16 [c=128][n=128], swizzled
    __shared__ __align__(16) int lab_s[2048];              // 8 KB
    __shared__ __align__(16) float4 pr[256];               // 4 KB  S1/S2 partials
    __shared__ float vacc[LL];
    __shared__ unsigned cnt[LL];

    const int tid  = threadIdx.x;
    const int wv   = tid >> 6;      // wave = 32-channel tile
    const int lane = tid & 63;

    const int b   = blockIdx.x / blk_per_b;
    const int blk = blockIdx.x % blk_per_b;
    const int pts = nchk * CHK;
    const int n0b = blk * pts;

    const float* __restrict__ predb = pred + (size_t)b * CC * NN;
    const int*   __restrict__ labb  = label + (size_t)b * NN + n0b;

    if (tid < LL) { vacc[tid] = 0.f; cnt[tid] = 0u; }
    for (int i = tid; i < (pts >> 2); i += 256)
        *(int4*)&lab_s[4*i] = *(const int4*)(labb + 4*i);
    __syncthreads();

    for (int i = tid; i < pts; i += 256) atomicAdd(&cnt[lab_s[i]], 1u);

    f32x16 acc0, acc1;
    #pragma unroll
    for (int i = 0; i < 16; ++i) { acc0[i] = 0.f; acc1[i] = 0.f; }

    const int src_c = tid & 127;    // staging row (channel)
    const int src_h = tid >> 7;     // staging half (64 pts)
    const int t0lab = lane & 31;
    const int khalf = lane >> 5;
    const int arow  = (wv << 5) + (lane & 31);

    for (int ch = 0; ch < nchk; ++ch) {
        const int n0 = n0b + ch * CHK;

        // ---- stage: 128x128 f32 -> bf16 LDS (coalesced), 16B-quad swizzle q^=c&15 ----
        const float* gp = predb + (size_t)src_c * NN + n0 + src_h * 64;
        float4 r[16];
        #pragma unroll
        for (int j = 0; j < 16; ++j) r[j] = *(const float4*)(gp + 4*j);
        #pragma unroll
        for (int i = 0; i < 8; ++i) {
            uint4 w;
            w.x = packbf(r[2*i].x,   r[2*i].y);
            w.y = packbf(r[2*i].z,   r[2*i].w);
            w.z = packbf(r[2*i+1].x, r[2*i+1].y);
            w.w = packbf(r[2*i+1].z, r[2*i+1].w);
            const int q  = 8*src_h + i;
            const int qs = q ^ (src_c & 15);
            *(uint4*)&pred_lds[src_c*64 + qs*4] = w;
        }
        __syncthreads();   // b1

        // ---- MFMA: A = pred[32ch x 16pts], B = onehot from label compares ----
        #pragma unroll
        for (int ks = 0; ks < 8; ++ks) {
            const int k0 = ks * 16;
            const int q  = (k0 >> 3) + khalf;
            const int qs = q ^ (arow & 15);
            V16 a; a.i = *(const int4*)&pred_lds[arow*64 + qs*4];
            const int lbase = ch*CHK + k0 + (khalf << 3);
            const int4 la = *(const int4*)&lab_s[lbase];
            const int4 lb = *(const int4*)&lab_s[lbase + 4];
            V16 b0, b1;
            b0.u = make_uint4(oh2(la.x,la.y,t0lab), oh2(la.z,la.w,t0lab),
                              oh2(lb.x,lb.y,t0lab), oh2(lb.z,lb.w,t0lab));
            const int t1lab = t0lab + 32;
            b1.u = make_uint4(oh2(la.x,la.y,t1lab), oh2(la.z,la.w,t1lab),
                              oh2(lb.x,lb.y,t1lab), oh2(lb.z,lb.w,t1lab));
            acc0 = __builtin_amdgcn_mfma_f32_32x32x16_bf16(a.s, b0.s, acc0, 0, 0, 0);
            acc1 = __builtin_amdgcn_mfma_f32_32x32x16_bf16(a.s, b1.s, acc1, 0, 0, 0);
        }

        // ---- S1/S2: transposed read, lane = point-pair, wave = 32-channel slice ----
        {
            const int p2 = tid & 63;
            float s1a=0.f, s2a=0.f, s1b=0.f, s2b=0.f;
            #pragma unroll
            for (int i2 = 0; i2 < 32; ++i2) {
                const int c  = (wv << 5) + i2;
                const int qs = (p2 >> 2) ^ (c & 15);
                const unsigned u = pred_lds[c*64 + qs*4 + (p2 & 3)];
                const float fa = __builtin_bit_cast(float, u << 16);
                const float fb = __builtin_bit_cast(float, u & 0xffff0000u);
                s1a += fa; s2a = fmaf(fa, fa, s2a);
                s1b += fb; s2b = fmaf(fb, fb, s2b);
            }
            pr[(p2 << 2) | wv] = make_float4(s1a, s2a, s1b, s2b);
        }
        __syncthreads();   // b2

        if (tid < 64) {
            const float4 t0 = pr[4*tid], t1 = pr[4*tid+1], t2 = pr[4*tid+2], t3 = pr[4*tid+3];
            const float s1 = t0.x+t1.x+t2.x+t3.x, s2 = t0.y+t1.y+t2.y+t3.y;
            const float u1 = t0.z+t1.z+t2.z+t3.z, u2 = t0.w+t1.w+t2.w+t3.w;
            float sqa = s2 - s1*s1*(1.0f/CC); sqa = sqa > 0.f ? sqa : 0.f;
            float sqb = u2 - u1*u1*(1.0f/CC); sqb = sqb > 0.f ? sqb : 0.f;
            const float da = sqrtf(sqa) - 0.5f, db = sqrtf(sqb) - 0.5f;
            const float va = da > 0.f ? da*da : 0.f, vb = db > 0.f ? db*db : 0.f;
            unsafeAtomicAdd(&vacc[lab_s[ch*CHK + 2*tid]], va);
            unsafeAtomicAdd(&vacc[lab_s[ch*CHK + 2*tid + 1]], vb);
        }
    }
    __syncthreads();

    // ---- flush: raw fragment order, perfectly coalesced float4 stores ----
    float* __restrict__ gp0 = gpart + (size_t)blockIdx.x * 8192 + wv*2048 + lane*4;
    #pragma unroll
    for (int j = 0; j < 4; ++j)
        *(float4*)(gp0 + j*256) = make_float4(acc0[4*j], acc0[4*j+1], acc0[4*j+2], acc0[4*j+3]);
    #pragma unroll
    for (int j = 0; j < 4; ++j)
        *(float4*)(gp0 + (j+4)*256) = make_float4(acc1[4*j], acc1[4*j+1], acc1[4*j+2], acc1[4*j+3]);

    if (tid < LL) {
        gcp[blockIdx.x*64 + tid] = (float)cnt[tid];
        gvp[blockIdx.x*64 + tid] = vacc[tid];
    }
}

// ---------------- kernel 1b: reduce partials, un-permute fragment layout ----------------
// blocks 0..255: (b, wv, jj) -> 256 gsum elements each. blocks 256..259: gcnt/gv.
__global__ __launch_bounds__(256)
void k1b_reduce(const float* __restrict__ gpart, const float* __restrict__ gcp,
                const float* __restrict__ gvp, float* __restrict__ gsum,
                float* __restrict__ gcnt, float* __restrict__ gv, int blk_per_b)
{
    const int kb = blockIdx.x, tid = threadIdx.x;
    if (kb < 256) {
        const int b = kb >> 5, wvj = kb & 31, wv = wvj >> 3, jj = wvj & 7;
        const float* p = gpart + (size_t)b * blk_per_b * 8192 + wv*2048 + jj*256 + tid;
        float s = 0.f;
        for (int k = 0; k < blk_per_b; ++k) s += p[(size_t)k * 8192];
        const int lane = tid >> 2, q = tid & 3;
        const int l   = (lane & 31) + ((jj >> 2) << 5);
        const int r2  = (jj & 3)*4 + q;
        const int chn = (wv << 5) + (r2 & 3) + ((r2 >> 2) << 3) + ((lane >> 5) << 2);
        gsum[b*8192 + l*128 + chn] = s;
    } else {
        const int idx = (kb - 256)*256 + tid;     // 0..1023
        const int which = idx >> 9;               // 0: gcnt, 1: gv
        const int o = idx & 511;                  // b*64 + l
        const int b = o >> 6, l = o & 63;
        const float* p = (which ? gvp : gcp) + (size_t)b * blk_per_b * 64 + l;
        float s = 0.f;
        for (int k = 0; k < blk_per_b; ++k) s += p[k*64];
        if (which) gv[o] = s; else gcnt[o] = s;
    }
}

// ---------------- kernel 2: finalize (tiny) ----------------
#define CEN_STRIDE 132

__global__ __launch_bounds__(256)
void k2_finalize(const float* __restrict__ gsum, const float* __restrict__ gcnt,
                 const float* __restrict__ gv, float* __restrict__ out)
{
    __shared__ float cen[LL * CEN_STRIDE];
    __shared__ float invc[LL];
    __shared__ float red[256];

    const int tid   = threadIdx.x;
    const int b     = blockIdx.x >> 3;
    const int strip = blockIdx.x & 7;

    if (tid < LL) invc[tid] = 1.0f / gcnt[b * LL + tid];
    __syncthreads();

    const float* __restrict__ gs = gsum + (size_t)b * LL * CC;
    for (int i = tid; i < LL * CC; i += 256) {
        const int l = i >> 7, c = i & 127;
        cen[l * CEN_STRIDE + c] = gs[i] * invc[l];
    }
    __syncthreads();

    const int c  = strip * 16 + (tid >> 4);
    const int d0 = (tid & 15) * 8;

    float areg[LL];
    #pragma unroll
    for (int l = 0; l < LL; ++l) areg[l] = cen[l * CEN_STRIDE + c];

    float sqd[8] = {0.f, 0.f, 0.f, 0.f, 0.f, 0.f, 0.f, 0.f};
    #pragma unroll
    for (int l = 0; l < LL; ++l) {
        const float4 b0 = *(const float4*)&cen[l * CEN_STRIDE + d0];
        const float4 b1 = *(const float4*)&cen[l * CEN_STRIDE + d0 + 4];
        const float a = areg[l];
        float t;
        t = a - b0.x; sqd[0] += t * t;
        t = a - b0.y; sqd[1] += t * t;
        t = a - b0.z; sqd[2] += t * t;
        t = a - b0.w; sqd[3] += t * t;
        t = a - b1.x; sqd[4] += t * t;
        t = a - b1.y; sqd[5] += t * t;
        t = a - b1.z; sqd[6] += t * t;
        t = a - b1.w; sqd[7] += t * t;
    }

    float hsum = 0.f;
    #pragma unroll
    for (int j = 0; j < 8; ++j) {
        const float dist = sqd[j] > 0.f ? sqrtf(sqd[j]) : 0.f;
        float h = 3.0f - dist;
        h = h > 0.f ? h : 0.f;
        hsum += h * h;
    }
    float my = hsum * (1.0f / 8064.0f);

    if (strip == 0) {
        if (tid < CC) {
            float s = 0.f;
            #pragma unroll
            for (int l = 0; l < LL; ++l) {
                const float v = cen[l * CEN_STRIDE + tid];
                s += v * v;
            }
            my += 0.001f * sqrtf(s) * (1.0f / LL);
        }
        if (tid < LL) {
            my += gv[b * LL + tid] * invc[tid] * (1.0f / LL);
        }
    }

    red[tid] = my;
    __syncthreads();
    for (int s = 128; s > 0; s >>= 1) {
        if (tid < s) red[tid] += red[tid + s];
        __syncthreads();
    }
    if (tid == 0) unsafeAtomicAdd(out, red[0]);
}

extern "C" void kernel_launch(void* const* d_in, const int* in_sizes, int n_in,
                              void* d_out, int out_size, void* d_ws, size_t ws_size,
                              hipStream_t stream) {
    (void)in_sizes; (void)n_in; (void)out_size;
    const float* pred  = (const float*)d_in[0];
    const int*   label = (const int*)d_in[1];
    float* out = (float*)d_out;

    // pick partial-buffer width by available workspace
    const size_t need64 = ((size_t)512*8192 + (size_t)512*128 + 65536 + 1024) * sizeof(float);
    const int blk_per_b = (ws_size >= need64) ? 64 : 32;
    const int nchk      = (NN / CHK) / blk_per_b;      // 8 or 16
    const int nblk      = BB * blk_per_b;              // 512 or 256

    float* gpart = (float*)d_ws;                       // [nblk][8192]
    float* gcp   = gpart + (size_t)nblk * 8192;        // [nblk][64]
    float* gvp   = gcp + (size_t)nblk * 64;            // [nblk][64]
    float* gsum  = gvp + (size_t)nblk * 64;            // [B][L][C]
    float* gcnt  = gsum + BB * LL * CC;                // [B][L]
    float* gv    = gcnt + BB * LL;                     // [B][L]

    hipMemsetAsync(d_out, 0, sizeof(float), stream);

    k1_mfma<<<nblk, 256, 0, stream>>>(pred, label, gpart, gcp, gvp, blk_per_b, nchk);
    k1b_reduce<<<260, 256, 0, stream>>>(gpart, gcp, gvp, gsum, gcnt, gv, blk_per_b);
    k2_finalize<<<BB * 8, 256, 0, stream>>>(gsum, gcnt, gv, out);
}